// Round 3
// baseline (496.835 us; speedup 1.0000x reference)
//
#include <hip/hip_runtime.h>
#include <math.h>

#define K_EMB 1024
#define D_DIM 256
#define T_SZ 2048
#define TOT 16777216        // B*D*T
#define LOSS_OFF 16777216
#define IDX_OFF 16777217
#define NDC 17              // 16 real d-chunks + 1 esq-fold chunk (A-side)
#define NCHUNK 34           // 2 k-halves x 17 dc
#define CHUNK_B 32768       // bytes/chunk: [2 hl][16 kcw][64 lane] x 16B

// kernel A dynamic LDS layout (bytes)
#define SM_XH   0           // 32,768  x hi frags: [tc2][dc16][64 lane][16B]
#define SM_XL   32768       // 32,768  x lo frags
#define SM_EB   65536       // 65,536  E-chunk double buffer (2 x 32KB)
#define SM_X2P  131072      //  2,048  per-thread x^2 partials (512 f32)
#define SM_REDV 133120      //  4,096  top2 vals [8w][2tcj][32m][2]
#define SM_REDK 137216      //  4,096  top2 keys
#define SM_TIE  141312      //    260  [0]=count, [1..64] packed tie entries
#define SM_TOT  141572

// kernel B dynamic LDS layout (bytes)
#define SMB_Q    0          // 65,792  64 rows x 257 f32 (stride 257: conflict-free)
#define SMB_IDX  65792      //    256  64 int
#define SMB_TOT  66048

typedef __attribute__((ext_vector_type(8)))  __bf16 bf16x8;
typedef __attribute__((ext_vector_type(8)))  short  s16x8;
typedef __attribute__((ext_vector_type(16))) float  f32x16;

__device__ __forceinline__ unsigned short f2bf(float f) {   // RNE fp32->bf16 bits
    unsigned u = __float_as_uint(f);
    u += 0x7FFFu + ((u >> 16) & 1u);
    return (unsigned short)(u >> 16);
}
__device__ __forceinline__ float bf2f(unsigned short h) {
    return __uint_as_float(((unsigned)h) << 16);
}
// top-2 insert, maximizing, tie -> smaller k (numpy first-occurrence argmin)
__device__ __forceinline__ void ins2(float& v1, int& k1, float& v2, int& k2,
                                     float v, int k) {
    bool b1 = (v > v1) || (v == v1 && k < k1);
    bool b2 = (v > v2) || (v == v2 && k < k2);
    if (b1) { v2 = v1; k2 = k1; v1 = v; k1 = k; }
    else if (b2) { v2 = v; k2 = k; }
}

// --- Kernel 0: pre-pack E into chunk-major MFMA A-frag order --------------
// chunk c = half*17 + dc holds k-tiles [half*16, half*16+16) at d-chunk dc:
// layout [hl2][kcw16][lane64] s16x8. Within a frag: A[m=lane&31][kd=(lane>>5)*8+j],
// k = kt*32+m, d = dc*16+(lane>>5)*8+j. dc==16 = esq-fold (h,q in hi; l in lo).
__global__ __launch_bounds__(256) void prepack_kernel(const float* __restrict__ E,
        unsigned short* __restrict__ Epk, float* __restrict__ loss) {
    if (blockIdx.x == 0 && threadIdx.x == 0) loss[0] = 0.f;
    int gid = blockIdx.x * 256 + threadIdx.x;        // == (kt*17+dc)*64 + lane
    if (gid >= 32 * NDC * 64) return;
    int lane = gid & 63;
    int dc = (gid >> 6) % NDC;
    int kt = gid / (NDC * 64);
    int m = lane & 31, dh = lane >> 5;
    int k = kt * 32 + m;
    unsigned short h8[8], l8[8];
#pragma unroll
    for (int j = 0; j < 8; ++j) { h8[j] = 0; l8[j] = 0; }
    if (dc < 16) {
        int d0 = dc * 16 + dh * 8;
        const float* ep = E + (size_t)k * D_DIM + d0;
#pragma unroll
        for (int j = 0; j < 8; ++j) {
            float e = ep[j];
            unsigned short hh = f2bf(e);
            h8[j] = hh;
            l8[j] = f2bf(e - bf2f(hh));
        }
    } else if (dh == 0) {
        const float* er = E + (size_t)k * D_DIM;
        float s0 = 0.f, s1 = 0.f, s2 = 0.f, s3 = 0.f;
        for (int i = 0; i < D_DIM; i += 4) {
            s0 = fmaf(er[i], er[i], s0);
            s1 = fmaf(er[i + 1], er[i + 1], s1);
            s2 = fmaf(er[i + 2], er[i + 2], s2);
            s3 = fmaf(er[i + 3], er[i + 3], s3);
        }
        float v = -0.5f * ((s0 + s1) + (s2 + s3));
        unsigned short h = f2bf(v);
        float r1 = v - bf2f(h);
        unsigned short l = f2bf(r1);
        float r2 = r1 - bf2f(l);
        unsigned short q = f2bf(r2);
        h8[0] = h; h8[1] = q; l8[0] = l;
    }
    s16x8 hv, lv;
#pragma unroll
    for (int j = 0; j < 8; ++j) { hv[j] = (short)h8[j]; lv[j] = (short)l8[j]; }
    int hh = kt >> 4, kcw = kt & 15;
    size_t dst = (size_t)(hh * NDC + dc) * 2048 + (size_t)kcw * 64 + lane;
    ((s16x8*)Epk)[dst] = hv;           // hl = 0 (hi plane)
    ((s16x8*)Epk)[dst + 1024] = lv;    // hl = 1 (lo plane, +16KB)
}

// async-stage one 32KB E-chunk into LDS: 32 x 1KB lines, wave w owns 4.
__device__ __forceinline__ void stage_chunk(const unsigned short* __restrict__ Epk,
                                            char* smem, int c, int w, int lane) {
    const char* gs = (const char*)Epk + (size_t)c * CHUNK_B
                     + (size_t)(w * 4) * 1024 + (size_t)lane * 16;
    char* ls = smem + SM_EB + (c & 1) * CHUNK_B + (w * 4) * 1024;
#pragma unroll
    for (int i = 0; i < 4; ++i) {
        __builtin_amdgcn_global_load_lds(
            (const __attribute__((address_space(1))) unsigned int*)(gs + i * 1024),
            (__attribute__((address_space(3))) unsigned int*)(ls + i * 1024),
            16, 0, 0);
    }
}

// --- Kernel A: argmin (split-bf16 MFMA) + loss + idx ----------------------
// 512 thr / 8 waves, t-tile 64 (2 tc). E-chunks (16 k-tiles x 1 dc, hi+lo)
// stream L2->LDS via global_load_lds, double-buffered 2-phase pipeline:
// issue chunk c+1, compute chunk c from LDS, __syncthreads (drains vmcnt).
// Chunk order is half-major so live acc = [2 kci][2 tcj] f32x16 = 64 VGPRs.
__global__ __launch_bounds__(512) void vq_argmin_kernel(
        const float* __restrict__ X, const unsigned short* __restrict__ Epk,
        const float* __restrict__ E, float* __restrict__ loss,
        float* __restrict__ idxf_out) {
    extern __shared__ char smem[];
    unsigned short* xhf = (unsigned short*)(smem + SM_XH);
    unsigned short* xlf = (unsigned short*)(smem + SM_XL);
    float* x2p = (float*)(smem + SM_X2P);
    float* redv = (float*)(smem + SM_REDV);
    int*   redk = (int*)(smem + SM_REDK);
    int*   tiec = (int*)(smem + SM_TIE);
    int*   tiel = tiec + 1;

    int tid = threadIdx.x;
    int lane = tid & 63;
    int w = tid >> 6;                        // 0..7
    int b = blockIdx.x >> 5;                 // 32 tiles of 64 t per b
    int tg0 = (blockIdx.x & 31) << 6;

    if (tid == 0) tiec[0] = 0;

    // issue chunk 0 loads first: they land while we stage X below
    stage_chunk(Epk, smem, 0, w, lane);

    // ---- stage X tile [64 t][256 d] -> frag-order bf16 hi/lo in LDS ----
    {
        int t = tid & 63, dblk = tid >> 6;   // 8 dblk x 32 d
        int tc = t >> 5, m = t & 31;
        const float* xp = X + (size_t)b * ((size_t)D_DIM * T_SZ) + tg0 + t;
        float x2a = 0.f;
        for (int g = 0; g < 4; ++g) {
            int d0 = dblk * 32 + g * 8;
            s16x8 hv, lv;
#pragma unroll
            for (int j = 0; j < 8; ++j) {
                float xv = xp[(size_t)(d0 + j) * T_SZ];
                unsigned short hh = f2bf(xv);
                hv[j] = (short)hh;
                lv[j] = (short)f2bf(xv - bf2f(hh));
                x2a = fmaf(xv, xv, x2a);
            }
            int dc = d0 >> 4, h = (d0 >> 3) & 1;
            int fi = (tc * 16 + dc) * 64 + h * 32 + m;
            ((s16x8*)xhf)[fi] = hv;
            ((s16x8*)xlf)[fi] = lv;
        }
        x2p[tid] = x2a;
    }
    __syncthreads();   // publishes X-frags AND drains chunk-0 global_load_lds

    int dhalf = lane >> 5;
    const s16x8* bhf = (const s16x8*)xhf;
    const s16x8* blf = (const s16x8*)xlf;

    s16x8 bfold = {0, 0, 0, 0, 0, 0, 0, 0};
    if (dhalf == 0) { bfold[0] = (short)0x3F80; bfold[1] = (short)0x3F80; }
    bf16x8 bh_fold = __builtin_bit_cast(bf16x8, bfold);

    float v1s[2], v2s[2];
    int k1s[2], k2s[2];
#pragma unroll
    for (int j = 0; j < 2; ++j) { v1s[j] = -INFINITY; v2s[j] = -INFINITY;
                                  k1s[j] = 0; k2s[j] = 0; }

    int cc = 0;
#pragma unroll 1
    for (int hh = 0; hh < 2; ++hh) {
        f32x16 acc[2][2];
#pragma unroll
        for (int kci = 0; kci < 2; ++kci)
#pragma unroll
            for (int tcj = 0; tcj < 2; ++tcj)
#pragma unroll
                for (int i = 0; i < 16; ++i) acc[kci][tcj][i] = 0.f;

#pragma unroll 1
        for (int dc = 0; dc < NDC; ++dc, ++cc) {
            if (cc < NCHUNK - 1) stage_chunk(Epk, smem, cc + 1, w, lane);

            const s16x8* eb = (const s16x8*)(smem + SM_EB + (cc & 1) * CHUNK_B);
            int e0 = (2 * w) * 64 + lane;            // hi plane, kci=0
            bf16x8 ah0 = __builtin_bit_cast(bf16x8, eb[e0]);
            bf16x8 ah1 = __builtin_bit_cast(bf16x8, eb[e0 + 64]);
            bf16x8 al0 = __builtin_bit_cast(bf16x8, eb[e0 + 1024]);
            bf16x8 al1 = __builtin_bit_cast(bf16x8, eb[e0 + 1088]);

            if (dc < 16) {
#pragma unroll
                for (int tcj = 0; tcj < 2; ++tcj) {
                    int fi = (tcj * 16 + dc) * 64 + lane;
                    bf16x8 bh = __builtin_bit_cast(bf16x8, bhf[fi]);
                    bf16x8 bl = __builtin_bit_cast(bf16x8, blf[fi]);
                    acc[0][tcj] = __builtin_amdgcn_mfma_f32_32x32x16_bf16(ah0, bh, acc[0][tcj], 0, 0, 0);
                    acc[0][tcj] = __builtin_amdgcn_mfma_f32_32x32x16_bf16(al0, bh, acc[0][tcj], 0, 0, 0);
                    acc[0][tcj] = __builtin_amdgcn_mfma_f32_32x32x16_bf16(ah0, bl, acc[0][tcj], 0, 0, 0);
                    acc[1][tcj] = __builtin_amdgcn_mfma_f32_32x32x16_bf16(ah1, bh, acc[1][tcj], 0, 0, 0);
                    acc[1][tcj] = __builtin_amdgcn_mfma_f32_32x32x16_bf16(al1, bh, acc[1][tcj], 0, 0, 0);
                    acc[1][tcj] = __builtin_amdgcn_mfma_f32_32x32x16_bf16(ah1, bl, acc[1][tcj], 0, 0, 0);
                }
            } else {
                // esq-fold chunk: B constant (1.0 in kd slots 0,1), B-lo == 0
#pragma unroll
                for (int tcj = 0; tcj < 2; ++tcj) {
                    acc[0][tcj] = __builtin_amdgcn_mfma_f32_32x32x16_bf16(ah0, bh_fold, acc[0][tcj], 0, 0, 0);
                    acc[0][tcj] = __builtin_amdgcn_mfma_f32_32x32x16_bf16(al0, bh_fold, acc[0][tcj], 0, 0, 0);
                    acc[1][tcj] = __builtin_amdgcn_mfma_f32_32x32x16_bf16(ah1, bh_fold, acc[1][tcj], 0, 0, 0);
                    acc[1][tcj] = __builtin_amdgcn_mfma_f32_32x32x16_bf16(al1, bh_fold, acc[1][tcj], 0, 0, 0);
                }
                // half complete: scan acc -> running top2 (ins2 is order-safe)
#pragma unroll
                for (int kci = 0; kci < 2; ++kci) {
                    int kb = (hh * 16 + 2 * w + kci) * 32 + 4 * dhalf;
#pragma unroll
                    for (int tcj = 0; tcj < 2; ++tcj)
#pragma unroll
                        for (int r = 0; r < 16; ++r) {
                            int kk = kb + (r & 3) + 8 * (r >> 2);
                            ins2(v1s[tcj], k1s[tcj], v2s[tcj], k2s[tcj],
                                 acc[kci][tcj][r], kk);
                        }
                }
            }
            __syncthreads();   // drains chunk c+1 loads; publishes buffer swap
        }
    }

    // merge lane^32 partner (same t, complementary k rows), store to LDS
#pragma unroll
    for (int tcj = 0; tcj < 2; ++tcj) {
        float pv1 = __shfl_xor(v1s[tcj], 32, 64); int pk1 = __shfl_xor(k1s[tcj], 32, 64);
        float pv2 = __shfl_xor(v2s[tcj], 32, 64); int pk2 = __shfl_xor(k2s[tcj], 32, 64);
        ins2(v1s[tcj], k1s[tcj], v2s[tcj], k2s[tcj], pv1, pk1);
        ins2(v1s[tcj], k1s[tcj], v2s[tcj], k2s[tcj], pv2, pk2);
        if (dhalf == 0) {
            int base = ((w * 2 + tcj) * 32 + (lane & 31)) * 2;
            redv[base] = v1s[tcj];     redk[base] = k1s[tcj];
            redv[base + 1] = v2s[tcj]; redk[base + 1] = k2s[tcj];
        }
    }
    __syncthreads();

    // per-t reduce across 8 waves; near-ties deferred to list
    if (tid < 64) {
        int t = tid, tcj = t >> 5, m = t & 31;
        float v1 = -INFINITY, v2 = -INFINITY;
        int k1 = 0, k2 = 0;
#pragma unroll
        for (int ww = 0; ww < 8; ++ww) {
            int base = ((ww * 2 + tcj) * 32 + m) * 2;
            ins2(v1, k1, v2, k2, redv[base], redk[base]);
            ins2(v1, k1, v2, k2, redv[base + 1], redk[base + 1]);
        }
        float dmin2 = 0.f;
        if (v1 - v2 < 0.005f) {   // near-tie: defer exact fp64 refinement
            int slot = atomicAdd(tiec, 1);
            tiel[slot] = (t << 20) | (k1 << 10) | k2;
        } else {
            idxf_out[(size_t)b * T_SZ + tg0 + t] = (float)k1;
            float x2 = 0.f;
#pragma unroll
            for (int i = 0; i < 8; ++i) x2 += x2p[t + 64 * i];
            dmin2 = x2 - 2.0f * v1;   // ||x||^2 - 2(x.e - esq/2) = ||x-e||^2
        }
        float lsum = dmin2;
#pragma unroll
        for (int off = 32; off > 0; off >>= 1) lsum += __shfl_down(lsum, off, 64);
        if (tid == 0) atomicAdd(loss, lsum * (0.5f / (float)TOT));
    }
    __syncthreads();

    // wave-parallel exact refinement: one wave per tie, 64 lanes x 4 d each
    {
        int ntie = tiec[0];
        for (int e = w; e < ntie; e += 8) {
            int pk = tiel[e];
            int t = pk >> 20;
            int k1 = (pk >> 10) & 1023, k2 = pk & 1023;
            const float* e1 = E + (size_t)k1 * D_DIM;
            const float* e2 = E + (size_t)k2 * D_DIM;
            const float* xc = X + (size_t)b * ((size_t)D_DIM * T_SZ) + tg0 + t;
            int d0 = lane * 4;
            double d1 = 0.0, d2 = 0.0;
#pragma unroll
            for (int u = 0; u < 4; ++u) {
                int d = d0 + u;
                double xd = (double)xc[(size_t)d * T_SZ];
                double u1 = xd - (double)e1[d];
                double u2 = xd - (double)e2[d];
                d1 += u1 * u1;
                d2 += u2 * u2;
            }
#pragma unroll
            for (int off = 32; off > 0; off >>= 1) {
                d1 += __shfl_down(d1, off, 64);
                d2 += __shfl_down(d2, off, 64);
            }
            if (lane == 0) {
                int kb = k1; double dm = d1;
                if (d2 < d1 || (d2 == d1 && k2 < k1)) { kb = k2; dm = d2; }
                idxf_out[(size_t)b * T_SZ + tg0 + t] = (float)kb;
                atomicAdd(loss, (float)dm * (0.5f / (float)TOT));
            }
        }
    }
}

// --- Kernel B: gather E rows by idx and write out0 [B,D,T] ----------------
// 64-t tile, 256 thr, 66 KB LDS -> 2 blocks/CU; pure streaming.
__global__ __launch_bounds__(256) void vq_gather_kernel(
        const float* __restrict__ E, const float* __restrict__ idxf,
        float* __restrict__ out0) {
    extern __shared__ char smemb[];
    float* q = (float*)(smemb + SMB_Q);      // [64][257]
    int* idxs = (int*)(smemb + SMB_IDX);
    int tid = threadIdx.x;
    int b = blockIdx.x >> 5;                 // 32 tiles of 64 t per b
    int tt0 = (blockIdx.x & 31) << 6;
    if (tid < 64) idxs[tid] = (int)idxf[(size_t)b * T_SZ + tt0 + tid];
    __syncthreads();
    // rows -> LDS (coalesced 1KB global reads; conflict-free LDS writes)
#pragma unroll 8
    for (int r = 0; r < 64; ++r) {
        int row = idxs[r];
        q[r * 257 + tid] = E[(size_t)row * D_DIM + tid];
    }
    __syncthreads();
    // write out0: lanes over t (coalesced 256B stores), LDS reads conflict-free
    int t = tid & 63, dgrp = tid >> 6;
    size_t obase = (size_t)b * ((size_t)D_DIM * T_SZ) + tt0 + t;
#pragma unroll 8
    for (int j = 0; j < 64; ++j) {
        int d = dgrp * 64 + j;
        out0[obase + (size_t)d * T_SZ] = q[t * 257 + d];
    }
}

extern "C" void kernel_launch(void* const* d_in, const int* in_sizes, int n_in,
                              void* d_out, int out_size, void* d_ws, size_t ws_size,
                              hipStream_t stream) {
    const float* X = (const float*)d_in[0];   // [32, 256, 2048] fp32
    const float* E = (const float*)d_in[1];   // [1024, 256] fp32
    float* out = (float*)d_out;
    float* loss = out + LOSS_OFF;
    float* idxf = out + IDX_OFF;

    unsigned short* Epk = (unsigned short*)d_ws;   // 34 chunks x 32KB = 1.09 MB

    prepack_kernel<<<(32 * NDC * 64 + 255) / 256, 256, 0, stream>>>(E, Epk, loss);
    vq_argmin_kernel<<<1024, 512, SM_TOT, stream>>>(X, Epk, E, loss, idxf);
    vq_gather_kernel<<<1024, 256, SMB_TOT, stream>>>(E, idxf, out);
}

// Round 4
// 361.026 us; speedup vs baseline: 1.3762x; 1.3762x over previous
//
#include <hip/hip_runtime.h>
#include <math.h>

#define K_EMB 1024
#define D_DIM 256
#define T_SZ 2048
#define TOT 16777216        // B*D*T
#define LOSS_OFF 16777216
#define IDX_OFF 16777217
#define NDC 17              // 16 real d-chunks + 1 esq-fold chunk (A-side)

// kernel A dynamic LDS layout (bytes)
#define SM_XH   0           // 65,536  x hi frags: [tc4][dc16][64 lanes][16B]
#define SM_XL   65536       // 65,536  x lo frags
#define SM_X2P  131072      //  4,096  per-thread x^2 partials (1024 f32)
#define SM_REDV 135168      //  8,192  top2 vals [16w][2tcj][32m][2]
#define SM_REDK 143360      //  8,192  top2 keys
#define SM_TIE  151552      //    516  [0]=count, [1..128] packed tie entries
#define SM_TOT  152068

// kernel B dynamic LDS layout (bytes)
#define SMB_Q    0          // 65,792  64 rows x 257 f32 (stride 257: conflict-free)
#define SMB_IDX  65792      //    256  64 int
#define SMB_TOT  66048

typedef __attribute__((ext_vector_type(8)))  __bf16 bf16x8;
typedef __attribute__((ext_vector_type(8)))  short  s16x8;
typedef __attribute__((ext_vector_type(16))) float  f32x16;

__device__ __forceinline__ unsigned short f2bf(float f) {   // RNE fp32->bf16 bits
    unsigned u = __float_as_uint(f);
    u += 0x7FFFu + ((u >> 16) & 1u);
    return (unsigned short)(u >> 16);
}
__device__ __forceinline__ float bf2f(unsigned short h) {
    return __uint_as_float(((unsigned)h) << 16);
}
// top-2 insert, maximizing, tie -> smaller k (numpy first-occurrence argmin).
// Insertion-order-safe: final (v1,k1,v2,k2) independent of visit order.
__device__ __forceinline__ void ins2(float& v1, int& k1, float& v2, int& k2,
                                     float v, int k) {
    bool b1 = (v > v1) || (v == v1 && k < k1);
    bool b2 = (v > v2) || (v == v2 && k < k2);
    if (b1) { v2 = v1; k2 = k1; v1 = v; k1 = k; }
    else if (b2) { v2 = v; k2 = k; }
}

// --- Kernel 0: pre-pack E into MFMA A-frag order, split bf16 hi/lo ---------
__global__ __launch_bounds__(256) void prepack_kernel(const float* __restrict__ E,
        unsigned short* __restrict__ Ehi, unsigned short* __restrict__ Elo,
        float* __restrict__ loss) {
    if (blockIdx.x == 0 && threadIdx.x == 0) loss[0] = 0.f;
    int gid = blockIdx.x * 256 + threadIdx.x;        // == (kc*17+dc)*64 + lane
    if (gid >= 32 * NDC * 64) return;
    int lane = gid & 63;
    int dc = (gid >> 6) % NDC;
    int kc = gid / (NDC * 64);
    int m = lane & 31, dh = lane >> 5;
    int k = kc * 32 + m;
    unsigned short h8[8], l8[8];
#pragma unroll
    for (int j = 0; j < 8; ++j) { h8[j] = 0; l8[j] = 0; }
    if (dc < 16) {
        int d0 = dc * 16 + dh * 8;
        const float* ep = E + (size_t)k * D_DIM + d0;
#pragma unroll
        for (int j = 0; j < 8; ++j) {
            float e = ep[j];
            unsigned short hh = f2bf(e);
            h8[j] = hh;
            l8[j] = f2bf(e - bf2f(hh));
        }
    } else if (dh == 0) {
        const float* er = E + (size_t)k * D_DIM;
        float s0 = 0.f, s1 = 0.f, s2 = 0.f, s3 = 0.f;
        for (int i = 0; i < D_DIM; i += 4) {
            s0 = fmaf(er[i], er[i], s0);
            s1 = fmaf(er[i + 1], er[i + 1], s1);
            s2 = fmaf(er[i + 2], er[i + 2], s2);
            s3 = fmaf(er[i + 3], er[i + 3], s3);
        }
        float v = -0.5f * ((s0 + s1) + (s2 + s3));
        unsigned short h = f2bf(v);
        float r1 = v - bf2f(h);
        unsigned short l = f2bf(r1);
        float r2 = r1 - bf2f(l);
        unsigned short q = f2bf(r2);
        h8[0] = h; h8[1] = q; l8[0] = l;
    }
    s16x8 hv, lv;
#pragma unroll
    for (int j = 0; j < 8; ++j) { hv[j] = (short)h8[j]; lv[j] = (short)l8[j]; }
    ((s16x8*)Ehi)[gid] = hv;
    ((s16x8*)Elo)[gid] = lv;
}

// --- Kernel A: argmin (split-bf16 MFMA) + loss + idx ----------------------
// 1024 thr / 16 waves (4/SIMD). Per kcg, wave w owns kc pair x tc pair:
// acc[2][2] f32x16 = 64 acc regs. L2 de-correlation: each block visits the
// 16 dc-chunks in a rotated order (rot staggered across same-XCD CUs) and
// kcg order hashed -> E-fragment reads spread across all L2 channels
// instead of all 256 CUs hammering the same lines each iteration.
__global__ __launch_bounds__(1024) void vq_argmin_kernel(
        const float* __restrict__ X, const unsigned short* __restrict__ Ehi,
        const unsigned short* __restrict__ Elo, const float* __restrict__ E,
        float* __restrict__ loss, float* __restrict__ idxf_out) {
    extern __shared__ char smem[];
    unsigned short* xhf = (unsigned short*)(smem + SM_XH);
    unsigned short* xlf = (unsigned short*)(smem + SM_XL);
    float* x2p = (float*)(smem + SM_X2P);
    float* redv = (float*)(smem + SM_REDV);
    int*   redk = (int*)(smem + SM_REDK);
    int*   tiec = (int*)(smem + SM_TIE);
    int*   tiel = tiec + 1;

    int tid = threadIdx.x;
    int b = blockIdx.x >> 4;                 // 16 tiles of 128 t per b
    int tg0 = (blockIdx.x & 15) << 7;
    int rot = (blockIdx.x >> 3) & 15;        // same-XCD CUs get different rot
    int kcswap = (blockIdx.x >> 7) & 1;      // coarse kcg-order hash

    if (tid == 0) tiec[0] = 0;

    // ---- stage X tile [128 t][256 d] -> frag-order bf16 hi/lo in LDS ----
    {
        int t = tid & 127, dblk = tid >> 7;  // 8 dblk x 32 d
        int tc = t >> 5, m = t & 31;
        const float* xp = X + (size_t)b * ((size_t)D_DIM * T_SZ) + tg0 + t;
        float x2a = 0.f;
        for (int g = 0; g < 4; ++g) {
            int d0 = dblk * 32 + g * 8;
            s16x8 hv, lv;
#pragma unroll
            for (int j = 0; j < 8; ++j) {
                float xv = xp[(size_t)(d0 + j) * T_SZ];
                unsigned short hh = f2bf(xv);
                hv[j] = (short)hh;
                lv[j] = (short)f2bf(xv - bf2f(hh));
                x2a = fmaf(xv, xv, x2a);
            }
            int dc = d0 >> 4, h = (d0 >> 3) & 1;
            int fi = (tc * 16 + dc) * 64 + h * 32 + m;
            ((s16x8*)xhf)[fi] = hv;
            ((s16x8*)xlf)[fi] = lv;
        }
        x2p[tid] = x2a;
    }
    __syncthreads();

    int lane = tid & 63;
    int w = tid >> 6;                        // 0..15
    int dhalf = lane >> 5;
    int kq = w >> 1;                         // 0..7: kc pair base 2*kq per kcg
    int tcb = (w & 1) * 2;                   // tc pair {tcb, tcb+1}

    const s16x8* ehp = (const s16x8*)Ehi;
    const s16x8* elp = (const s16x8*)Elo;
    const s16x8* bhf = (const s16x8*)xhf;
    const s16x8* blf = (const s16x8*)xlf;

    s16x8 bfold = {0, 0, 0, 0, 0, 0, 0, 0};
    if (dhalf == 0) { bfold[0] = (short)0x3F80; bfold[1] = (short)0x3F80; }
    bf16x8 bh_fold = __builtin_bit_cast(bf16x8, bfold);

    float v1s[2], v2s[2];
    int k1s[2], k2s[2];
#pragma unroll
    for (int j = 0; j < 2; ++j) { v1s[j] = -INFINITY; v2s[j] = -INFINITY;
                                  k1s[j] = 0; k2s[j] = 0; }

#pragma unroll 1
    for (int kcgi = 0; kcgi < 2; ++kcgi) {
        int kcg = kcgi ^ kcswap;             // k-order permute: bit-exact safe
        int kcb = kcg * 16 + kq * 2;         // owns kcb, kcb+1
        f32x16 acc[2][2];
#pragma unroll
        for (int kci = 0; kci < 2; ++kci)
#pragma unroll
            for (int tcj = 0; tcj < 2; ++tcj)
#pragma unroll
                for (int i = 0; i < 16; ++i) acc[kci][tcj][i] = 0.f;

#pragma unroll 1
        for (int dci = 0; dci < 16; ++dci) {
            int dc = (dci + rot) & 15;       // rotated visit order per block
            int fi0 = (tcb * 16 + dc) * 64 + lane;
            int fi1 = ((tcb + 1) * 16 + dc) * 64 + lane;
            bf16x8 bh0 = __builtin_bit_cast(bf16x8, bhf[fi0]);
            bf16x8 bl0 = __builtin_bit_cast(bf16x8, blf[fi0]);
            bf16x8 bh1 = __builtin_bit_cast(bf16x8, bhf[fi1]);
            bf16x8 bl1 = __builtin_bit_cast(bf16x8, blf[fi1]);
            size_t a0 = ((size_t)kcb * NDC + dc) * 64 + lane;
            {
                bf16x8 ah = __builtin_bit_cast(bf16x8, ehp[a0]);
                bf16x8 al = __builtin_bit_cast(bf16x8, elp[a0]);
                acc[0][0] = __builtin_amdgcn_mfma_f32_32x32x16_bf16(ah, bh0, acc[0][0], 0, 0, 0);
                acc[0][0] = __builtin_amdgcn_mfma_f32_32x32x16_bf16(al, bh0, acc[0][0], 0, 0, 0);
                acc[0][0] = __builtin_amdgcn_mfma_f32_32x32x16_bf16(ah, bl0, acc[0][0], 0, 0, 0);
                acc[0][1] = __builtin_amdgcn_mfma_f32_32x32x16_bf16(ah, bh1, acc[0][1], 0, 0, 0);
                acc[0][1] = __builtin_amdgcn_mfma_f32_32x32x16_bf16(al, bh1, acc[0][1], 0, 0, 0);
                acc[0][1] = __builtin_amdgcn_mfma_f32_32x32x16_bf16(ah, bl1, acc[0][1], 0, 0, 0);
            }
            {
                bf16x8 ah = __builtin_bit_cast(bf16x8, ehp[a0 + NDC * 64]);
                bf16x8 al = __builtin_bit_cast(bf16x8, elp[a0 + NDC * 64]);
                acc[1][0] = __builtin_amdgcn_mfma_f32_32x32x16_bf16(ah, bh0, acc[1][0], 0, 0, 0);
                acc[1][0] = __builtin_amdgcn_mfma_f32_32x32x16_bf16(al, bh0, acc[1][0], 0, 0, 0);
                acc[1][0] = __builtin_amdgcn_mfma_f32_32x32x16_bf16(ah, bl0, acc[1][0], 0, 0, 0);
                acc[1][1] = __builtin_amdgcn_mfma_f32_32x32x16_bf16(ah, bh1, acc[1][1], 0, 0, 0);
                acc[1][1] = __builtin_amdgcn_mfma_f32_32x32x16_bf16(al, bh1, acc[1][1], 0, 0, 0);
                acc[1][1] = __builtin_amdgcn_mfma_f32_32x32x16_bf16(ah, bl1, acc[1][1], 0, 0, 0);
            }
        }
        {   // esq-fold chunk (dc==16, always last): B constant, B-lo == 0
            size_t a0 = ((size_t)kcb * NDC + 16) * 64 + lane;
            bf16x8 ah0 = __builtin_bit_cast(bf16x8, ehp[a0]);
            bf16x8 al0 = __builtin_bit_cast(bf16x8, elp[a0]);
            bf16x8 ah1 = __builtin_bit_cast(bf16x8, ehp[a0 + NDC * 64]);
            bf16x8 al1 = __builtin_bit_cast(bf16x8, elp[a0 + NDC * 64]);
#pragma unroll
            for (int tcj = 0; tcj < 2; ++tcj) {
                acc[0][tcj] = __builtin_amdgcn_mfma_f32_32x32x16_bf16(ah0, bh_fold, acc[0][tcj], 0, 0, 0);
                acc[0][tcj] = __builtin_amdgcn_mfma_f32_32x32x16_bf16(al0, bh_fold, acc[0][tcj], 0, 0, 0);
                acc[1][tcj] = __builtin_amdgcn_mfma_f32_32x32x16_bf16(ah1, bh_fold, acc[1][tcj], 0, 0, 0);
                acc[1][tcj] = __builtin_amdgcn_mfma_f32_32x32x16_bf16(al1, bh_fold, acc[1][tcj], 0, 0, 0);
            }
        }
        // scan acc -> per-tcj running top2 (ins2 is insertion-order-safe)
#pragma unroll
        for (int kci = 0; kci < 2; ++kci) {
            int kb = (kcb + kci) * 32 + 4 * dhalf;
#pragma unroll
            for (int tcj = 0; tcj < 2; ++tcj)
#pragma unroll
                for (int r = 0; r < 16; ++r) {
                    int kk = kb + (r & 3) + 8 * (r >> 2);
                    ins2(v1s[tcj], k1s[tcj], v2s[tcj], k2s[tcj], acc[kci][tcj][r], kk);
                }
        }
    }

    // merge lane^32 partner (same t, complementary k rows), store to LDS
#pragma unroll
    for (int tcj = 0; tcj < 2; ++tcj) {
        float pv1 = __shfl_xor(v1s[tcj], 32, 64); int pk1 = __shfl_xor(k1s[tcj], 32, 64);
        float pv2 = __shfl_xor(v2s[tcj], 32, 64); int pk2 = __shfl_xor(k2s[tcj], 32, 64);
        ins2(v1s[tcj], k1s[tcj], v2s[tcj], k2s[tcj], pv1, pk1);
        ins2(v1s[tcj], k1s[tcj], v2s[tcj], k2s[tcj], pv2, pk2);
        if (dhalf == 0) {
            int base = ((w * 2 + tcj) * 32 + (lane & 31)) * 2;
            redv[base] = v1s[tcj];     redk[base] = k1s[tcj];
            redv[base + 1] = v2s[tcj]; redk[base + 1] = k2s[tcj];
        }
    }
    __syncthreads();

    // per-t reduce across the 8 contributing waves; near-ties deferred
    if (tid < 128) {
        int t = tid, tc = t >> 5, m = t & 31;
        int wpar = tc >> 1, tcj = tc & 1;    // wave parity / tcj for this tc
        float v1 = -INFINITY, v2 = -INFINITY;
        int k1 = 0, k2 = 0;
#pragma unroll
        for (int qq = 0; qq < 8; ++qq) {
            int ww = qq * 2 + wpar;
            int base = ((ww * 2 + tcj) * 32 + m) * 2;
            ins2(v1, k1, v2, k2, redv[base], redk[base]);
            ins2(v1, k1, v2, k2, redv[base + 1], redk[base + 1]);
        }
        float dmin2 = 0.f;
        if (v1 - v2 < 0.005f) {   // near-tie: defer exact fp64 refinement
            int slot = atomicAdd(tiec, 1);
            tiel[slot] = (t << 20) | (k1 << 10) | k2;
        } else {
            idxf_out[(size_t)b * T_SZ + tg0 + t] = (float)k1;
            float x2 = 0.f;
#pragma unroll
            for (int i = 0; i < 8; ++i) x2 += x2p[t + 128 * i];
            dmin2 = x2 - 2.0f * v1;   // ||x||^2 - 2(x.e - esq/2) = ||x-e||^2
        }
        float lsum = dmin2;
#pragma unroll
        for (int off = 32; off > 0; off >>= 1) lsum += __shfl_down(lsum, off, 64);
        if ((tid & 63) == 0) atomicAdd(loss, lsum * (0.5f / (float)TOT));
    }
    __syncthreads();

    // wave-parallel exact refinement: one wave per tie, 64 lanes x 4 d each
    {
        int ntie = tiec[0];
        for (int e = w; e < ntie; e += 16) {
            int pk = tiel[e];
            int t = pk >> 20;
            int k1 = (pk >> 10) & 1023, k2 = pk & 1023;
            const float* e1 = E + (size_t)k1 * D_DIM;
            const float* e2 = E + (size_t)k2 * D_DIM;
            const float* xc = X + (size_t)b * ((size_t)D_DIM * T_SZ) + tg0 + t;
            int d0 = lane * 4;
            double d1 = 0.0, d2 = 0.0;
#pragma unroll
            for (int u = 0; u < 4; ++u) {
                int d = d0 + u;
                double xd = (double)xc[(size_t)d * T_SZ];
                double u1 = xd - (double)e1[d];
                double u2 = xd - (double)e2[d];
                d1 += u1 * u1;
                d2 += u2 * u2;
            }
#pragma unroll
            for (int off = 32; off > 0; off >>= 1) {
                d1 += __shfl_down(d1, off, 64);
                d2 += __shfl_down(d2, off, 64);
            }
            if (lane == 0) {
                int kb = k1; double dm = d1;
                if (d2 < d1 || (d2 == d1 && k2 < k1)) { kb = k2; dm = d2; }
                idxf_out[(size_t)b * T_SZ + tg0 + t] = (float)kb;
                atomicAdd(loss, (float)dm * (0.5f / (float)TOT));
            }
        }
    }
}

// --- Kernel B: gather E rows by idx and write out0 [B,D,T] ----------------
// 64-t tile, 256 thr, 66 KB LDS -> 2 blocks/CU; pure streaming.
__global__ __launch_bounds__(256) void vq_gather_kernel(
        const float* __restrict__ E, const float* __restrict__ idxf,
        float* __restrict__ out0) {
    extern __shared__ char smemb[];
    float* q = (float*)(smemb + SMB_Q);      // [64][257]
    int* idxs = (int*)(smemb + SMB_IDX);
    int tid = threadIdx.x;
    int b = blockIdx.x >> 5;                 // 32 tiles of 64 t per b
    int tt0 = (blockIdx.x & 31) << 6;
    if (tid < 64) idxs[tid] = (int)idxf[(size_t)b * T_SZ + tt0 + tid];
    __syncthreads();
    // rows -> LDS (coalesced 1KB global reads; conflict-free LDS writes)
#pragma unroll 8
    for (int r = 0; r < 64; ++r) {
        int row = idxs[r];
        q[r * 257 + tid] = E[(size_t)row * D_DIM + tid];
    }
    __syncthreads();
    // write out0: lanes over t (coalesced 256B stores), LDS reads conflict-free
    int t = tid & 63, dgrp = tid >> 6;
    size_t obase = (size_t)b * ((size_t)D_DIM * T_SZ) + tt0 + t;
#pragma unroll 8
    for (int j = 0; j < 64; ++j) {
        int d = dgrp * 64 + j;
        out0[obase + (size_t)d * T_SZ] = q[t * 257 + d];
    }
}

extern "C" void kernel_launch(void* const* d_in, const int* in_sizes, int n_in,
                              void* d_out, int out_size, void* d_ws, size_t ws_size,
                              hipStream_t stream) {
    const float* X = (const float*)d_in[0];   // [32, 256, 2048] fp32
    const float* E = (const float*)d_in[1];   // [1024, 256] fp32
    float* out = (float*)d_out;
    float* loss = out + LOSS_OFF;
    float* idxf = out + IDX_OFF;

    unsigned short* Ehi = (unsigned short*)d_ws;                 // 544 KB
    unsigned short* Elo = (unsigned short*)((char*)d_ws + 32 * NDC * 64 * 8 * 2);

    prepack_kernel<<<(32 * NDC * 64 + 255) / 256, 256, 0, stream>>>(E, Ehi, Elo, loss);
    vq_argmin_kernel<<<512, 1024, SM_TOT, stream>>>(X, Ehi, Elo, E, loss, idxf);
    vq_gather_kernel<<<1024, 256, SMB_TOT, stream>>>(E, idxf, out);
}